// Round 13
// baseline (220.326 us; speedup 1.0000x reference)
//
#include <hip/hip_runtime.h>

typedef __attribute__((ext_vector_type(8))) short bf16x8;
typedef __attribute__((ext_vector_type(4))) float f32x4;
typedef unsigned int u32;

__device__ __forceinline__ unsigned short f2bf(float f) {
  union { float f; unsigned int u; } a; a.f = f;
  unsigned int u = a.u;
  u += 0x7FFFu + ((u >> 16) & 1u);   // RNE
  return (unsigned short)(u >> 16);
}

// async global->LDS, 16B per lane. LDS dest = wave-uniform base + lane*16.
__device__ __forceinline__ void gload16(const unsigned short* g, unsigned short* l) {
  __builtin_amdgcn_global_load_lds((const __attribute__((address_space(1))) u32*)g,
                                   (__attribute__((address_space(3))) u32*)l, 16, 0, 0);
}

#define BK 64
// Ledger: R13 coarse pipeline REGRESSED. R15 128^2 tiles REGRESSED. R16
// scores2w NULL pre-swizzle. R18 8-phase TV NULL. R19 prep_mt REGRESSED.
// R20 XCD swizzle scores/PV WIN 217->204. R21 scores2wz(2-wave)+mt64 WIN
// 201.9 best. R22 swizzled TV REGRESSED 212.5. R23 unswizzled tv2 203.3:
// TV bounces 43-50 on identical source (rule-#19 lottery); WRITE_SIZE
// attribution is eviction-timing-soft. R24 pv2w: 2-wave 64x64 PV geometry,
// per-stripe blocks (1024, 8 waves/CU), balanced-s XCD decode.
// R25: round-12 bench was an infra failure (container failed twice, no
// profile) - 3rd occurrence (R1, R4 cleared on resubmit). pv2w re-audited:
// decode bijective, bounds in-range, barriers uniform, epilogue = MODE-3
// math. No defect found. Resubmitting unchanged.

// ---------------- Mt on 64x64 tiles, full-GPU grid (R21) ----------------
// Mt[j][i] = sum_o Wkb[j][o] Wqb[i][o]. 256 blocks (16x16), 256 thr, 4 waves
// each owning 16m x 64n. LDS 16KB. Same XOR-chunk swizzle everywhere.
__global__ __launch_bounds__(256, 4)
void mt64(const unsigned short* __restrict__ Wkb,
          const unsigned short* __restrict__ Wqb,
          unsigned short* __restrict__ Mt)
{
  int bm = blockIdx.y * 64, bn = blockIdx.x * 64;
  __shared__ __align__(16) unsigned short As[64 * 64];
  __shared__ __align__(16) unsigned short Bs[64 * 64];

  int tid  = threadIdx.x;
  int wave = tid >> 6, lane = tid & 63;
  int quad = lane >> 4, l16 = lane & 15;
  int r8 = lane >> 3;
  int c  = (lane & 7) ^ r8;
  const unsigned short* Ag = Wkb + (long)(bm + wave * 16 + r8) * 1024 + c * 8;
  const unsigned short* Bg = Wqb + (long)(bn + wave * 16 + r8) * 1024 + c * 8;
  unsigned short* Al = &As[(wave * 16) * 64];
  unsigned short* Bl = &Bs[(wave * 16) * 64];

  f32x4 acc[4] = {};

  for (int k0 = 0; k0 < 1024; k0 += 64) {
#pragma unroll
    for (int g = 0; g < 2; g++)
      gload16(Ag + k0 + (long)g * 8 * 1024, Al + g * 8 * 64);
#pragma unroll
    for (int g = 0; g < 2; g++)
      gload16(Bg + k0 + (long)g * 8 * 1024, Bl + g * 8 * 64);
    __syncthreads();

#pragma unroll
    for (int h = 0; h < 2; h++) {
      bf16x8 af, bfr[4];
      af = *(const bf16x8*)&As[(wave * 16 + l16) * 64 + (((quad + 4 * h) ^ (l16 & 7)) * 8)];
#pragma unroll
      for (int j = 0; j < 4; j++)
        bfr[j] = *(const bf16x8*)&Bs[(j * 16 + l16) * 64 + (((quad + 4 * h) ^ (l16 & 7)) * 8)];
#pragma unroll
      for (int j = 0; j < 4; j++)
        acc[j] = __builtin_amdgcn_mfma_f32_16x16x32_bf16(af, bfr[j], acc[j], 0, 0, 0);
    }
    __syncthreads();
  }

  int grow0 = bm + wave * 16 + quad * 4;
#pragma unroll
  for (int j = 0; j < 4; j++) {
    int gcol = bn + j * 16 + l16;
#pragma unroll
    for (int r = 0; r < 4; r++)
      Mt[(long)(grow0 + r) * 1024 + gcol] = f2bf(acc[j][r]);
  }
}

// ---------------- scores, 2-wave blocks + XCD swizzle (R21 WIN) ----------
// Per-wave 64x64 output, block tile 128x64, 1088-block tri grid, LDS 24KB.
__global__ __launch_bounds__(128, 3)
void scores2wz(const unsigned short* __restrict__ T,   // [b][2048][1024]
               const unsigned short* __restrict__ Xb,  // [b][2048][1024]
               float* __restrict__ rsum,               // [b][2048]
               unsigned short* __restrict__ E,         // [b][2048][2048]
               float scale)
{
  // XCD swizzle then triangular decode over 128x64 tiles (272/batch)
  int flat = blockIdx.x + 272 * blockIdx.z;        // 1088 total
  int rm   = (flat & 7) * 136 + (flat >> 3);       // bijective
  int z = rm / 272;
  int f = rm % 272;
  int r = (int)((sqrtf((float)(4 * f + 1)) - 1.0f) * 0.5f);
  while ((r + 1) * (r + 2) <= f) r++;
  while (r * (r + 1) > f) r--;
  int bm0 = r * 128;
  int bn  = (f - r * (r + 1)) * 64;

  const unsigned short* A = T  + (long)z * 2048 * 1024;
  const unsigned short* B = Xb + (long)z * 2048 * 1024;
  unsigned short* Cb = E + (long)z * 2048 * 2048;
  float* Cf = rsum + (long)z * 2048;

  __shared__ __align__(16) unsigned short As[128 * BK];  // 16 KB
  __shared__ __align__(16) unsigned short Bs[64 * BK];   //  8 KB

  int tid  = threadIdx.x;
  int wave = tid >> 6, lane = tid & 63;
  int quad = lane >> 4, l16 = lane & 15;
  int wm   = wave * 64;                 // wave owns 64 rows x all 64 cols

  // staging lane coords: 8-row groups, chunk XOR-swizzled (row%8-invariant)
  int r8 = lane >> 3;
  int c  = (lane & 7) ^ r8;
  const unsigned short* Ag = A + (long)(bm0 + wave * 64 + r8) * 1024 + c * 8;
  const unsigned short* Bg = B + (long)(bn  + wave * 32 + r8) * 1024 + c * 8;
  unsigned short* Al = &As[(wave * 64) * BK];
  unsigned short* Bl = &Bs[(wave * 32) * BK];

  f32x4 acc[4][4] = {};

  for (int k0 = 0; k0 < 1024; k0 += BK) {
#pragma unroll
    for (int g = 0; g < 8; g++)        // A: 64 rows per wave
      gload16(Ag + k0 + (long)g * 8 * 1024, Al + g * 8 * BK);
#pragma unroll
    for (int g = 0; g < 4; g++)        // B: 32 rows per wave
      gload16(Bg + k0 + (long)g * 8 * 1024, Bl + g * 8 * BK);
    __syncthreads();

#pragma unroll
    for (int h = 0; h < 2; h++) {
      bf16x8 af[4], bfr[4];
#pragma unroll
      for (int i = 0; i < 4; i++)
        af[i]  = *(const bf16x8*)&As[(wm + i * 16 + l16) * BK + (((quad + 4 * h) ^ (l16 & 7)) * 8)];
#pragma unroll
      for (int j = 0; j < 4; j++)
        bfr[j] = *(const bf16x8*)&Bs[(j * 16 + l16) * BK + (((quad + 4 * h) ^ (l16 & 7)) * 8)];
#pragma unroll
      for (int i = 0; i < 4; i++)
#pragma unroll
        for (int j = 0; j < 4; j++)
          acc[i][j] = __builtin_amdgcn_mfma_f32_16x16x32_bf16(af[i], bfr[j], acc[i][j], 0, 0, 0);
    }
    __syncthreads();
  }

  // Epilogue: E = exp(C*scale) masked col<=row + row-sum atomics
#pragma unroll
  for (int i = 0; i < 4; i++) {
    int grow0 = bm0 + wm + i * 16 + quad * 4;
#pragma unroll
    for (int rr = 0; rr < 4; rr++) {
      int grow = grow0 + rr;
      float rowpart = 0.f;
#pragma unroll
      for (int j = 0; j < 4; j++) {
        int gcol = bn + j * 16 + l16;
        float e = (gcol <= grow) ? __expf(acc[i][j][rr] * scale) : 0.f;
        rowpart += e;
        Cb[(long)grow * 2048 + gcol] = f2bf(e);
      }
      rowpart += __shfl_xor(rowpart, 1);
      rowpart += __shfl_xor(rowpart, 2);
      rowpart += __shfl_xor(rowpart, 4);
      rowpart += __shfl_xor(rowpart, 8);
      if (l16 == 0) atomicAdd(&Cf[grow], rowpart);
    }
  }
}

// ---------------- fused TV, 2-barrier 128x128, UNSWIZZLED (R23) ----------
// 256 thr, 4 waves (2x2), per-wave 64x64, LDS 32KB, 4 blocks/CU.
__global__ __launch_bounds__(256, 4)
void gemm_tv2(const unsigned short* __restrict__ A,   // Xb [8192][1024]
              const unsigned short* __restrict__ Bm,  // TVB [2048][1024]
              unsigned short* __restrict__ Cb)        // T ; Vt
{
  int bm0 = blockIdx.y * 128;
  int bn  = blockIdx.x * 128;

  __shared__ __align__(16) unsigned short As[128 * BK];
  __shared__ __align__(16) unsigned short Bs[128 * BK];

  int tid  = threadIdx.x;
  int wave = tid >> 6, lane = tid & 63;
  int wm = (wave >> 1) * 64;
  int wn = (wave & 1) * 64;
  int quad = lane >> 4, l16 = lane & 15;

  // staging lane coords: 8-row groups, chunk XOR-swizzled (row%8-invariant)
  int r8 = lane >> 3;
  int c  = (lane & 7) ^ r8;
  const unsigned short* Ag = A  + (long)(bm0 + wave * 32 + r8) * 1024 + c * 8;
  const unsigned short* Bg = Bm + (long)(bn  + wave * 32 + r8) * 1024 + c * 8;
  unsigned short* Al = &As[(wave * 32) * BK];
  unsigned short* Bl = &Bs[(wave * 32) * BK];

  f32x4 acc[4][4] = {};

  for (int k0 = 0; k0 < 1024; k0 += BK) {
#pragma unroll
    for (int g = 0; g < 4; g++)
      gload16(Ag + k0 + (long)g * 8 * 1024, Al + g * 8 * BK);
#pragma unroll
    for (int g = 0; g < 4; g++)
      gload16(Bg + k0 + (long)g * 8 * 1024, Bl + g * 8 * BK);
    __syncthreads();

#pragma unroll
    for (int h = 0; h < 2; h++) {
      bf16x8 af[4], bfr[4];
#pragma unroll
      for (int i = 0; i < 4; i++)
        af[i]  = *(const bf16x8*)&As[(wm + i * 16 + l16) * BK + (((quad + 4 * h) ^ (l16 & 7)) * 8)];
#pragma unroll
      for (int j = 0; j < 4; j++)
        bfr[j] = *(const bf16x8*)&Bs[(wn + j * 16 + l16) * BK + (((quad + 4 * h) ^ (l16 & 7)) * 8)];
#pragma unroll
      for (int i = 0; i < 4; i++)
#pragma unroll
        for (int j = 0; j < 4; j++)
          acc[i][j] = __builtin_amdgcn_mfma_f32_16x16x32_bf16(af[i], bfr[j], acc[i][j], 0, 0, 0);
    }
    __syncthreads();
  }

  // TV split epilogue. C/D layout: col = lane&15, row = quad*4 + reg
#pragma unroll
  for (int i = 0; i < 4; i++) {
    int grow0 = bm0 + wm + i * 16 + quad * 4;
#pragma unroll
    for (int j = 0; j < 4; j++) {
      int gcol = bn + wn + j * 16 + l16;
      int which = gcol >> 10;           // wave-uniform (bn,wn multiples of 64)
      int col = gcol & 1023;
      if (which == 0) {                 // T bf16 row-major [8192][1024]
#pragma unroll
        for (int r = 0; r < 4; r++)
          Cb[(long)(grow0 + r) * 1024 + col] = f2bf(acc[i][j][r]);
      } else {                          // Vt[b][col][s], 4-row pack along s
        unsigned short* Vt = Cb + (long)8192 * 1024;
        int bb = grow0 >> 11, s = grow0 & 2047;
        ushort4 pk;
        pk.x = f2bf(acc[i][j][0]); pk.y = f2bf(acc[i][j][1]);
        pk.z = f2bf(acc[i][j][2]); pk.w = f2bf(acc[i][j][3]);
        *(ushort4*)(Vt + ((long)bb * 1024 + col) * 2048 + s) = pk;
      }
    }
  }
}

// ---------------- R24: PV, 2-wave blocks, per-stripe, balanced XCD ------
// Per-wave 64x64 (32 MFMA : 16 ds_read per K-step), block 128 rows x 64
// cols, one stripe s per block, Keff = (s+1)*128. Grid 16x16x4 = 1024
// blocks x 2 waves = 8 waves/CU. XCD decode: each 128-chunk contains ALL
// stripe sizes (s alternation 15,0,14,1,...) -> balanced K-work per XCD;
// same-col blocks adjacent -> Vt 64-col panel L2-resident. LDS 24KB.
__global__ __launch_bounds__(128, 3)
void pv2w(const unsigned short* __restrict__ Em,   // [b][2048][2048]
          const unsigned short* __restrict__ Vt,   // [b][1024][2048]
          float* __restrict__ outp,                // [b][2048][1024]
          const float* __restrict__ rsum)          // [b][2048]
{
  int flat = blockIdx.x + 16 * blockIdx.y + 256 * blockIdx.z;  // 1024 total
  int rm   = (flat & 7) * 128 + (flat >> 3);       // bijective
  int z    = rm >> 8;
  int w    = rm & 255;
  int col  = w >> 4;
  int q    = w & 15;
  int s    = (q & 1) ? (q >> 1) : (15 - (q >> 1)); // 15,0,14,1,... balanced
  int bm   = s * 128;
  int bn   = col * 64;
  int Keff = (s + 1) * 128;

  const unsigned short* A = Em + (long)z * 2048 * 2048;
  const unsigned short* B = Vt + (long)z * 1024 * 2048;
  float* C       = outp + (long)z * 2048 * 1024;
  const float* R = rsum + (long)z * 2048;

  __shared__ __align__(16) unsigned short As[128 * BK];  // 16 KB
  __shared__ __align__(16) unsigned short Bs[64 * BK];   //  8 KB

  int tid  = threadIdx.x;
  int wave = tid >> 6, lane = tid & 63;
  int quad = lane >> 4, l16 = lane & 15;
  int wm   = wave * 64;                 // wave owns 64 rows x all 64 cols

  // staging lane coords: 8-row groups, chunk XOR-swizzled (row%8-invariant)
  int r8 = lane >> 3;
  int c  = (lane & 7) ^ r8;
  const unsigned short* Ag = A + (long)(bm + wave * 64 + r8) * 2048 + c * 8;
  const unsigned short* Bg = B + (long)(bn + wave * 32 + r8) * 2048 + c * 8;
  unsigned short* Al = &As[(wave * 64) * BK];
  unsigned short* Bl = &Bs[(wave * 32) * BK];

  f32x4 acc[4][4] = {};

  for (int k0 = 0; k0 < Keff; k0 += BK) {
#pragma unroll
    for (int g = 0; g < 8; g++)        // A (E): 64 rows per wave
      gload16(Ag + k0 + (long)g * 8 * 2048, Al + g * 8 * BK);
#pragma unroll
    for (int g = 0; g < 4; g++)        // B (Vt): 32 rows per wave
      gload16(Bg + k0 + (long)g * 8 * 2048, Bl + g * 8 * BK);
    __syncthreads();

#pragma unroll
    for (int h = 0; h < 2; h++) {
      bf16x8 af[4], bfr[4];
#pragma unroll
      for (int i = 0; i < 4; i++)
        af[i]  = *(const bf16x8*)&As[(wm + i * 16 + l16) * BK + (((quad + 4 * h) ^ (l16 & 7)) * 8)];
#pragma unroll
      for (int j = 0; j < 4; j++)
        bfr[j] = *(const bf16x8*)&Bs[(j * 16 + l16) * BK + (((quad + 4 * h) ^ (l16 & 7)) * 8)];
#pragma unroll
      for (int i = 0; i < 4; i++)
#pragma unroll
        for (int j = 0; j < 4; j++)
          acc[i][j] = __builtin_amdgcn_mfma_f32_16x16x32_bf16(af[i], bfr[j], acc[i][j], 0, 0, 0);
    }
    __syncthreads();
  }

  // Epilogue: out = acc / rsum[row]
#pragma unroll
  for (int i = 0; i < 4; i++) {
    int grow0 = bm + wm + i * 16 + quad * 4;
    float rinv[4];
#pragma unroll
    for (int r = 0; r < 4; r++) rinv[r] = 1.0f / R[grow0 + r];
#pragma unroll
    for (int j = 0; j < 4; j++) {
      int gcol = bn + j * 16 + l16;
#pragma unroll
      for (int r = 0; r < 4; r++)
        C[(long)(grow0 + r) * 1024 + gcol] = acc[i][j][r] * rinv[r];
    }
  }
}

// fused prep: [0,8192) x->bf16; [8192,9216) Wq->bf16 (NO transpose);
// [9216,10240) Wk->bf16 (NO transpose); [10240,11264) Wv transpose-convert;
// [11264,11272) zero rsum
__global__ __launch_bounds__(256)
void prep(const float* __restrict__ x,
          const float* __restrict__ W0, const float* __restrict__ W1,
          const float* __restrict__ W2,
          unsigned short* __restrict__ Xb,
          unsigned short* __restrict__ Wqb, unsigned short* __restrict__ Wkb,
          unsigned short* __restrict__ WvT,
          float* __restrict__ rsum)
{
  __shared__ float tile[32][33];
  int b = blockIdx.x;
  if (b < 8192) {
    long i = ((long)b * 256 + threadIdx.x) * 4;
    float4 v = *(const float4*)(x + i);
    ushort4 o;
    o.x = f2bf(v.x); o.y = f2bf(v.y); o.z = f2bf(v.z); o.w = f2bf(v.w);
    *(ushort4*)(Xb + i) = o;
  } else if (b < 10240) {
    int t = b - 8192;
    const float* W    = (t < 1024) ? W0 : W1;
    unsigned short* D = (t < 1024) ? Wqb : Wkb;
    long i = ((long)(t & 1023) * 256 + threadIdx.x) * 4;
    float4 v = *(const float4*)(W + i);
    ushort4 o;
    o.x = f2bf(v.x); o.y = f2bf(v.y); o.z = f2bf(v.z); o.w = f2bf(v.w);
    *(ushort4*)(D + i) = o;
  } else if (b < 11264) {
    int q = b - 10240;
    int kb = (q >> 5) * 32, nb = (q & 31) * 32;
    int tx = threadIdx.x & 31, ty = threadIdx.x >> 5;
    for (int r = ty; r < 32; r += 8)
      tile[r][tx] = W2[(long)(kb + r) * 1024 + nb + tx];
    __syncthreads();
    for (int r = ty; r < 32; r += 8)
      WvT[(long)(nb + r) * 1024 + kb + tx] = f2bf(tile[tx][r]);
  } else {
    long i = ((long)(b - 11264) * 256 + threadIdx.x) * 4;
    float4 zz = {0.f, 0.f, 0.f, 0.f};
    *(float4*)(rsum + i) = zz;
  }
}

extern "C" void kernel_launch(void* const* d_in, const int* in_sizes, int n_in,
                              void* d_out, int out_size, void* d_ws, size_t ws_size,
                              hipStream_t stream) {
  const float* x  = (const float*)d_in[0];
  const float* Wq = (const float*)d_in[1];
  const float* Wk = (const float*)d_in[2];
  const float* Wv = (const float*)d_in[3];
  float* out = (float*)d_out;

  // workspace layout (bf16 = unsigned short), ~120 MB
  unsigned short* Xb  = (unsigned short*)d_ws;            // [8192][1024]
  unsigned short* Wqb = Xb  + (long)8192 * 1024;          // [1024][1024] bf16 [in][out]
  unsigned short* Wkb = Wqb + (long)1024 * 1024;          // [1024][1024] bf16 [in][out]
  unsigned short* TVB = Wkb + (long)1024 * 1024;          // [2048][1024]: Mt ; WvT
  unsigned short* T   = TVB + (long)2048 * 1024;          // [8192][1024]
  unsigned short* Vt  = T   + (long)8192 * 1024;          // [4][1024][2048] (follows T!)
  unsigned short* E   = Vt  + (long)8192 * 1024;          // [4][2048][2048] bf16 exp(s)
  float* rsum         = (float*)(E + (long)4 * 2048 * 2048); // [4][2048] fp32

  prep<<<11272, 256, 0, stream>>>(x, Wq, Wk, Wv, Xb, Wqb, Wkb,
                                  TVB + (long)1024 * 1024, rsum);

  // Mt[j][i] = sum_o Wk[j][o] Wq[i][o] = M[i][j], M = Wq Wk^T (full-GPU grid)
  mt64<<<dim3(16, 16, 1), 256, 0, stream>>>(Wkb, Wqb, TVB);

  // fused TV: [8192x2048] = Xb * [Mt;WvT]^T; robust 2-barrier, unswizzled
  gemm_tv2<<<dim3(16, 64, 1), 256, 0, stream>>>(Xb, TVB, T);

  // E = exp(T * Xb^T / 32) masked lower-tri + row sums; 2-wave + XCD swizzle
  scores2wz<<<dim3(272, 1, 4), 128, 0, stream>>>(T, Xb, rsum, E, 0.03125f);

  // out = (E * Vt^T)/rsum; 2-wave per-stripe blocks, balanced XCD decode
  pv2w<<<dim3(16, 16, 4), 128, 0, stream>>>(E, Vt, out, rsum);
}

// Round 14
// 208.066 us; speedup vs baseline: 1.0589x; 1.0589x over previous
//
#include <hip/hip_runtime.h>

typedef __attribute__((ext_vector_type(8))) short bf16x8;
typedef __attribute__((ext_vector_type(4))) float f32x4;
typedef unsigned int u32;

__device__ __forceinline__ unsigned short f2bf(float f) {
  union { float f; unsigned int u; } a; a.f = f;
  unsigned int u = a.u;
  u += 0x7FFFu + ((u >> 16) & 1u);   // RNE
  return (unsigned short)(u >> 16);
}

// async global->LDS, 16B per lane. LDS dest = wave-uniform base + lane*16.
__device__ __forceinline__ void gload16(const unsigned short* g, unsigned short* l) {
  __builtin_amdgcn_global_load_lds((const __attribute__((address_space(1))) u32*)g,
                                   (__attribute__((address_space(3))) u32*)l, 16, 0, 0);
}

#define BK 64
// Ledger: R20 XCD swizzle scores/PV WIN 217->204. R21 scores2wz(2-wave)+mt64
// WIN 201.9 best. R22 TV-swizzle REGRESSED. R23 unswizzled tv2 203.3 (TV
// lottery 43-50 on identical source). R25 pv2w REGRESSED +18us: per-stripe
// blocks have 16:1 work variance and the WHOLE grid is resident from t=0 ->
// no dynamic rebalancing; short-stripe blocks drain, s=15 blocks finish at
// ~4 waves/CU. Stripe-pairing existed to fix exactly this.
// R26: pv2wp = stripe-pairing (uniform 34 iters/block) + 2-wave 64x64
// geometry (32 MFMA : 12 ds_read per K-step). Single-variable A/B vs
// gemm_bt<3>: same grid/pairing/swizzle, only block geometry changes.
// If >=35us, 2-wave PV closes; revert to R23 exact next round.

// ---------------- Mt on 64x64 tiles, full-GPU grid (R21) ----------------
__global__ __launch_bounds__(256, 4)
void mt64(const unsigned short* __restrict__ Wkb,
          const unsigned short* __restrict__ Wqb,
          unsigned short* __restrict__ Mt)
{
  int bm = blockIdx.y * 64, bn = blockIdx.x * 64;
  __shared__ __align__(16) unsigned short As[64 * 64];
  __shared__ __align__(16) unsigned short Bs[64 * 64];

  int tid  = threadIdx.x;
  int wave = tid >> 6, lane = tid & 63;
  int quad = lane >> 4, l16 = lane & 15;
  int r8 = lane >> 3;
  int c  = (lane & 7) ^ r8;
  const unsigned short* Ag = Wkb + (long)(bm + wave * 16 + r8) * 1024 + c * 8;
  const unsigned short* Bg = Wqb + (long)(bn + wave * 16 + r8) * 1024 + c * 8;
  unsigned short* Al = &As[(wave * 16) * 64];
  unsigned short* Bl = &Bs[(wave * 16) * 64];

  f32x4 acc[4] = {};

  for (int k0 = 0; k0 < 1024; k0 += 64) {
#pragma unroll
    for (int g = 0; g < 2; g++)
      gload16(Ag + k0 + (long)g * 8 * 1024, Al + g * 8 * 64);
#pragma unroll
    for (int g = 0; g < 2; g++)
      gload16(Bg + k0 + (long)g * 8 * 1024, Bl + g * 8 * 64);
    __syncthreads();

#pragma unroll
    for (int h = 0; h < 2; h++) {
      bf16x8 af, bfr[4];
      af = *(const bf16x8*)&As[(wave * 16 + l16) * 64 + (((quad + 4 * h) ^ (l16 & 7)) * 8)];
#pragma unroll
      for (int j = 0; j < 4; j++)
        bfr[j] = *(const bf16x8*)&Bs[(j * 16 + l16) * 64 + (((quad + 4 * h) ^ (l16 & 7)) * 8)];
#pragma unroll
      for (int j = 0; j < 4; j++)
        acc[j] = __builtin_amdgcn_mfma_f32_16x16x32_bf16(af, bfr[j], acc[j], 0, 0, 0);
    }
    __syncthreads();
  }

  int grow0 = bm + wave * 16 + quad * 4;
#pragma unroll
  for (int j = 0; j < 4; j++) {
    int gcol = bn + j * 16 + l16;
#pragma unroll
    for (int r = 0; r < 4; r++)
      Mt[(long)(grow0 + r) * 1024 + gcol] = f2bf(acc[j][r]);
  }
}

// ---------------- scores, 2-wave blocks + XCD swizzle (R21 WIN) ----------
__global__ __launch_bounds__(128, 3)
void scores2wz(const unsigned short* __restrict__ T,   // [b][2048][1024]
               const unsigned short* __restrict__ Xb,  // [b][2048][1024]
               float* __restrict__ rsum,               // [b][2048]
               unsigned short* __restrict__ E,         // [b][2048][2048]
               float scale)
{
  // XCD swizzle then triangular decode over 128x64 tiles (272/batch)
  int flat = blockIdx.x + 272 * blockIdx.z;        // 1088 total
  int rm   = (flat & 7) * 136 + (flat >> 3);       // bijective
  int z = rm / 272;
  int f = rm % 272;
  int r = (int)((sqrtf((float)(4 * f + 1)) - 1.0f) * 0.5f);
  while ((r + 1) * (r + 2) <= f) r++;
  while (r * (r + 1) > f) r--;
  int bm0 = r * 128;
  int bn  = (f - r * (r + 1)) * 64;

  const unsigned short* A = T  + (long)z * 2048 * 1024;
  const unsigned short* B = Xb + (long)z * 2048 * 1024;
  unsigned short* Cb = E + (long)z * 2048 * 2048;
  float* Cf = rsum + (long)z * 2048;

  __shared__ __align__(16) unsigned short As[128 * BK];  // 16 KB
  __shared__ __align__(16) unsigned short Bs[64 * BK];   //  8 KB

  int tid  = threadIdx.x;
  int wave = tid >> 6, lane = tid & 63;
  int quad = lane >> 4, l16 = lane & 15;
  int wm   = wave * 64;                 // wave owns 64 rows x all 64 cols

  // staging lane coords: 8-row groups, chunk XOR-swizzled (row%8-invariant)
  int r8 = lane >> 3;
  int c  = (lane & 7) ^ r8;
  const unsigned short* Ag = A + (long)(bm0 + wave * 64 + r8) * 1024 + c * 8;
  const unsigned short* Bg = B + (long)(bn  + wave * 32 + r8) * 1024 + c * 8;
  unsigned short* Al = &As[(wave * 64) * BK];
  unsigned short* Bl = &Bs[(wave * 32) * BK];

  f32x4 acc[4][4] = {};

  for (int k0 = 0; k0 < 1024; k0 += BK) {
#pragma unroll
    for (int g = 0; g < 8; g++)        // A: 64 rows per wave
      gload16(Ag + k0 + (long)g * 8 * 1024, Al + g * 8 * BK);
#pragma unroll
    for (int g = 0; g < 4; g++)        // B: 32 rows per wave
      gload16(Bg + k0 + (long)g * 8 * 1024, Bl + g * 8 * BK);
    __syncthreads();

#pragma unroll
    for (int h = 0; h < 2; h++) {
      bf16x8 af[4], bfr[4];
#pragma unroll
      for (int i = 0; i < 4; i++)
        af[i]  = *(const bf16x8*)&As[(wm + i * 16 + l16) * BK + (((quad + 4 * h) ^ (l16 & 7)) * 8)];
#pragma unroll
      for (int j = 0; j < 4; j++)
        bfr[j] = *(const bf16x8*)&Bs[(j * 16 + l16) * BK + (((quad + 4 * h) ^ (l16 & 7)) * 8)];
#pragma unroll
      for (int i = 0; i < 4; i++)
#pragma unroll
        for (int j = 0; j < 4; j++)
          acc[i][j] = __builtin_amdgcn_mfma_f32_16x16x32_bf16(af[i], bfr[j], acc[i][j], 0, 0, 0);
    }
    __syncthreads();
  }

  // Epilogue: E = exp(C*scale) masked col<=row + row-sum atomics
#pragma unroll
  for (int i = 0; i < 4; i++) {
    int grow0 = bm0 + wm + i * 16 + quad * 4;
#pragma unroll
    for (int rr = 0; rr < 4; rr++) {
      int grow = grow0 + rr;
      float rowpart = 0.f;
#pragma unroll
      for (int j = 0; j < 4; j++) {
        int gcol = bn + j * 16 + l16;
        float e = (gcol <= grow) ? __expf(acc[i][j][rr] * scale) : 0.f;
        rowpart += e;
        Cb[(long)grow * 2048 + gcol] = f2bf(e);
      }
      rowpart += __shfl_xor(rowpart, 1);
      rowpart += __shfl_xor(rowpart, 2);
      rowpart += __shfl_xor(rowpart, 4);
      rowpart += __shfl_xor(rowpart, 8);
      if (l16 == 0) atomicAdd(&Cf[grow], rowpart);
    }
  }
}

// ---------------- fused TV, 2-barrier 128x128, UNSWIZZLED (R23) ----------
__global__ __launch_bounds__(256, 4)
void gemm_tv2(const unsigned short* __restrict__ A,   // Xb [8192][1024]
              const unsigned short* __restrict__ Bm,  // TVB [2048][1024]
              unsigned short* __restrict__ Cb)        // T ; Vt
{
  int bm0 = blockIdx.y * 128;
  int bn  = blockIdx.x * 128;

  __shared__ __align__(16) unsigned short As[128 * BK];
  __shared__ __align__(16) unsigned short Bs[128 * BK];

  int tid  = threadIdx.x;
  int wave = tid >> 6, lane = tid & 63;
  int wm = (wave >> 1) * 64;
  int wn = (wave & 1) * 64;
  int quad = lane >> 4, l16 = lane & 15;

  // staging lane coords: 8-row groups, chunk XOR-swizzled (row%8-invariant)
  int r8 = lane >> 3;
  int c  = (lane & 7) ^ r8;
  const unsigned short* Ag = A  + (long)(bm0 + wave * 32 + r8) * 1024 + c * 8;
  const unsigned short* Bg = Bm + (long)(bn  + wave * 32 + r8) * 1024 + c * 8;
  unsigned short* Al = &As[(wave * 32) * BK];
  unsigned short* Bl = &Bs[(wave * 32) * BK];

  f32x4 acc[4][4] = {};

  for (int k0 = 0; k0 < 1024; k0 += BK) {
#pragma unroll
    for (int g = 0; g < 4; g++)
      gload16(Ag + k0 + (long)g * 8 * 1024, Al + g * 8 * BK);
#pragma unroll
    for (int g = 0; g < 4; g++)
      gload16(Bg + k0 + (long)g * 8 * 1024, Bl + g * 8 * BK);
    __syncthreads();

#pragma unroll
    for (int h = 0; h < 2; h++) {
      bf16x8 af[4], bfr[4];
#pragma unroll
      for (int i = 0; i < 4; i++)
        af[i]  = *(const bf16x8*)&As[(wm + i * 16 + l16) * BK + (((quad + 4 * h) ^ (l16 & 7)) * 8)];
#pragma unroll
      for (int j = 0; j < 4; j++)
        bfr[j] = *(const bf16x8*)&Bs[(wn + j * 16 + l16) * BK + (((quad + 4 * h) ^ (l16 & 7)) * 8)];
#pragma unroll
      for (int i = 0; i < 4; i++)
#pragma unroll
        for (int j = 0; j < 4; j++)
          acc[i][j] = __builtin_amdgcn_mfma_f32_16x16x32_bf16(af[i], bfr[j], acc[i][j], 0, 0, 0);
    }
    __syncthreads();
  }

  // TV split epilogue. C/D layout: col = lane&15, row = quad*4 + reg
#pragma unroll
  for (int i = 0; i < 4; i++) {
    int grow0 = bm0 + wm + i * 16 + quad * 4;
#pragma unroll
    for (int j = 0; j < 4; j++) {
      int gcol = bn + wn + j * 16 + l16;
      int which = gcol >> 10;           // wave-uniform (bn,wn multiples of 64)
      int col = gcol & 1023;
      if (which == 0) {                 // T bf16 row-major [8192][1024]
#pragma unroll
        for (int r = 0; r < 4; r++)
          Cb[(long)(grow0 + r) * 1024 + col] = f2bf(acc[i][j][r]);
      } else {                          // Vt[b][col][s], 4-row pack along s
        unsigned short* Vt = Cb + (long)8192 * 1024;
        int bb = grow0 >> 11, s = grow0 & 2047;
        ushort4 pk;
        pk.x = f2bf(acc[i][j][0]); pk.y = f2bf(acc[i][j][1]);
        pk.z = f2bf(acc[i][j][2]); pk.w = f2bf(acc[i][j][3]);
        *(ushort4*)(Vt + ((long)bb * 1024 + col) * 2048 + s) = pk;
      }
    }
  }
}

// ---------------- R26: PV, stripe-paired 2-wave blocks ----------------
// Uniform work (seg0 = stripe 15-p K=(16-p)*128, seg1 = stripe p K=(p+1)*128
// -> 34 iters/block) + 2-wave 64x64 per-wave geometry (32 MFMA : 12 ds_read
// per K-step). Grid (16,8,4) = 512 blocks x 2 waves = 4 waves/CU; operands
// are L3-class (E 32MB just written, Vt 16MB). Same XCD swizzle as the
// proven gemm_bt<3>. LDS 24KB.
__global__ __launch_bounds__(128, 3)
void pv2wp(const unsigned short* __restrict__ Em,   // [b][2048][2048]
           const unsigned short* __restrict__ Vt,   // [b][1024][2048]
           float* __restrict__ outp,                // [b][2048][1024]
           const float* __restrict__ rsum)          // [b][2048]
{
  int flat = blockIdx.x + 16 * blockIdx.y + 128 * blockIdx.z;  // 512 total
  int rm   = (flat & 7) * 64 + (flat >> 3);        // bijective
  int z  = rm >> 7;
  int p  = (rm >> 4) & 7;
  int bn = (rm & 15) * 64;

  const unsigned short* A = Em + (long)z * 2048 * 2048;
  const unsigned short* B = Vt + (long)z * 1024 * 2048;
  float* C       = outp + (long)z * 2048 * 1024;
  const float* R = rsum + (long)z * 2048;

  __shared__ __align__(16) unsigned short As[128 * BK];  // 16 KB
  __shared__ __align__(16) unsigned short Bs[64 * BK];   //  8 KB

  int tid  = threadIdx.x;
  int wave = tid >> 6, lane = tid & 63;
  int quad = lane >> 4, l16 = lane & 15;
  int wm   = wave * 64;                 // wave owns 64 rows x all 64 cols

  // staging lane coords: 8-row groups, chunk XOR-swizzled (row%8-invariant)
  int r8 = lane >> 3;
  int c  = (lane & 7) ^ r8;
  const unsigned short* Bg = B + (long)(bn + wave * 32 + r8) * 2048 + c * 8;
  unsigned short* Al = &As[(wave * 64) * BK];
  unsigned short* Bl = &Bs[(wave * 32) * BK];

  for (int seg = 0; seg < 2; seg++) {
    int bm   = (seg == 0) ? (15 - p) * 128 : p * 128;
    int Keff = (seg == 0) ? (16 - p) * 128 : (p + 1) * 128;
    const unsigned short* Ag = A + (long)(bm + wave * 64 + r8) * 2048 + c * 8;

    f32x4 acc[4][4] = {};

    for (int k0 = 0; k0 < Keff; k0 += BK) {
#pragma unroll
      for (int g = 0; g < 8; g++)      // A (E): 64 rows per wave
        gload16(Ag + k0 + (long)g * 8 * 2048, Al + g * 8 * BK);
#pragma unroll
      for (int g = 0; g < 4; g++)      // B (Vt): 32 rows per wave
        gload16(Bg + k0 + (long)g * 8 * 2048, Bl + g * 8 * BK);
      __syncthreads();

#pragma unroll
      for (int h = 0; h < 2; h++) {
        bf16x8 af[4], bfr[4];
#pragma unroll
        for (int i = 0; i < 4; i++)
          af[i]  = *(const bf16x8*)&As[(wm + i * 16 + l16) * BK + (((quad + 4 * h) ^ (l16 & 7)) * 8)];
#pragma unroll
        for (int j = 0; j < 4; j++)
          bfr[j] = *(const bf16x8*)&Bs[(j * 16 + l16) * BK + (((quad + 4 * h) ^ (l16 & 7)) * 8)];
#pragma unroll
        for (int i = 0; i < 4; i++)
#pragma unroll
          for (int j = 0; j < 4; j++)
            acc[i][j] = __builtin_amdgcn_mfma_f32_16x16x32_bf16(af[i], bfr[j], acc[i][j], 0, 0, 0);
      }
      __syncthreads();
    }

    // Epilogue: out = acc / rsum[row]
#pragma unroll
    for (int i = 0; i < 4; i++) {
      int grow0 = bm + wm + i * 16 + quad * 4;
      float rinv[4];
#pragma unroll
      for (int r = 0; r < 4; r++) rinv[r] = 1.0f / R[grow0 + r];
#pragma unroll
      for (int j = 0; j < 4; j++) {
        int gcol = bn + j * 16 + l16;
#pragma unroll
        for (int r = 0; r < 4; r++)
          C[(long)(grow0 + r) * 1024 + gcol] = acc[i][j][r] * rinv[r];
      }
    }
  }
}

// fused prep: [0,8192) x->bf16; [8192,9216) Wq->bf16 (NO transpose);
// [9216,10240) Wk->bf16 (NO transpose); [10240,11264) Wv transpose-convert;
// [11264,11272) zero rsum
__global__ __launch_bounds__(256)
void prep(const float* __restrict__ x,
          const float* __restrict__ W0, const float* __restrict__ W1,
          const float* __restrict__ W2,
          unsigned short* __restrict__ Xb,
          unsigned short* __restrict__ Wqb, unsigned short* __restrict__ Wkb,
          unsigned short* __restrict__ WvT,
          float* __restrict__ rsum)
{
  __shared__ float tile[32][33];
  int b = blockIdx.x;
  if (b < 8192) {
    long i = ((long)b * 256 + threadIdx.x) * 4;
    float4 v = *(const float4*)(x + i);
    ushort4 o;
    o.x = f2bf(v.x); o.y = f2bf(v.y); o.z = f2bf(v.z); o.w = f2bf(v.w);
    *(ushort4*)(Xb + i) = o;
  } else if (b < 10240) {
    int t = b - 8192;
    const float* W    = (t < 1024) ? W0 : W1;
    unsigned short* D = (t < 1024) ? Wqb : Wkb;
    long i = ((long)(t & 1023) * 256 + threadIdx.x) * 4;
    float4 v = *(const float4*)(W + i);
    ushort4 o;
    o.x = f2bf(v.x); o.y = f2bf(v.y); o.z = f2bf(v.z); o.w = f2bf(v.w);
    *(ushort4*)(D + i) = o;
  } else if (b < 11264) {
    int q = b - 10240;
    int kb = (q >> 5) * 32, nb = (q & 31) * 32;
    int tx = threadIdx.x & 31, ty = threadIdx.x >> 5;
    for (int r = ty; r < 32; r += 8)
      tile[r][tx] = W2[(long)(kb + r) * 1024 + nb + tx];
    __syncthreads();
    for (int r = ty; r < 32; r += 8)
      WvT[(long)(nb + r) * 1024 + kb + tx] = f2bf(tile[tx][r]);
  } else {
    long i = ((long)(b - 11264) * 256 + threadIdx.x) * 4;
    float4 zz = {0.f, 0.f, 0.f, 0.f};
    *(float4*)(rsum + i) = zz;
  }
}

extern "C" void kernel_launch(void* const* d_in, const int* in_sizes, int n_in,
                              void* d_out, int out_size, void* d_ws, size_t ws_size,
                              hipStream_t stream) {
  const float* x  = (const float*)d_in[0];
  const float* Wq = (const float*)d_in[1];
  const float* Wk = (const float*)d_in[2];
  const float* Wv = (const float*)d_in[3];
  float* out = (float*)d_out;

  // workspace layout (bf16 = unsigned short), ~120 MB
  unsigned short* Xb  = (unsigned short*)d_ws;            // [8192][1024]
  unsigned short* Wqb = Xb  + (long)8192 * 1024;          // [1024][1024] bf16 [in][out]
  unsigned short* Wkb = Wqb + (long)1024 * 1024;          // [1024][1024] bf16 [in][out]
  unsigned short* TVB = Wkb + (long)1024 * 1024;          // [2048][1024]: Mt ; WvT
  unsigned short* T   = TVB + (long)2048 * 1024;          // [8192][1024]
  unsigned short* Vt  = T   + (long)8192 * 1024;          // [4][1024][2048] (follows T!)
  unsigned short* E   = Vt  + (long)8192 * 1024;          // [4][2048][2048] bf16 exp(s)
  float* rsum         = (float*)(E + (long)4 * 2048 * 2048); // [4][2048] fp32

  prep<<<11272, 256, 0, stream>>>(x, Wq, Wk, Wv, Xb, Wqb, Wkb,
                                  TVB + (long)1024 * 1024, rsum);

  // Mt[j][i] = sum_o Wk[j][o] Wq[i][o] = M[i][j], M = Wq Wk^T (full-GPU grid)
  mt64<<<dim3(16, 16, 1), 256, 0, stream>>>(Wkb, Wqb, TVB);

  // fused TV: [8192x2048] = Xb * [Mt;WvT]^T; robust 2-barrier, unswizzled
  gemm_tv2<<<dim3(16, 64, 1), 256, 0, stream>>>(Xb, TVB, T);

  // E = exp(T * Xb^T / 32) masked lower-tri + row sums; 2-wave + XCD swizzle
  scores2wz<<<dim3(272, 1, 4), 128, 0, stream>>>(T, Xb, rsum, E, 0.03125f);

  // out = (E * Vt^T)/rsum; stripe-paired 2-wave blocks + XCD swizzle
  pv2wp<<<dim3(16, 8, 4), 128, 0, stream>>>(E, Vt, out, rsum);
}

// Round 15
// 201.888 us; speedup vs baseline: 1.0913x; 1.0306x over previous
//
#include <hip/hip_runtime.h>

typedef __attribute__((ext_vector_type(8))) short bf16x8;
typedef __attribute__((ext_vector_type(4))) float f32x4;
typedef unsigned int u32;

__device__ __forceinline__ unsigned short f2bf(float f) {
  union { float f; unsigned int u; } a; a.f = f;
  unsigned int u = a.u;
  u += 0x7FFFu + ((u >> 16) & 1u);   // RNE
  return (unsigned short)(u >> 16);
}

// async global->LDS, 16B per lane. LDS dest = wave-uniform base + lane*16.
__device__ __forceinline__ void gload16(const unsigned short* g, unsigned short* l) {
  __builtin_amdgcn_global_load_lds((const __attribute__((address_space(1))) u32*)g,
                                   (__attribute__((address_space(3))) u32*)l, 16, 0, 0);
}

#define BK 64
// R27 FINAL: byte-exact revert to the Round-9/R21 source - the session's
// best measured build (201.9us). Compilation is deterministic; the 43-50us
// cross-build swings on identical kernel source were sibling-set codegen
// perturbation (rule #19), so reproducing the exact translation unit
// reproduces the measurement.
// Session ledger: R13 coarse pipeline REGRESSED (57). R15 128^2 tiles
// REGRESSED (~46/kernel). R16 scores2w NULL pre-swizzle. R18 8-phase TV
// NULL (44 healthy; fragile under sibling drift -> 68.5 in this build, still
// net-best total). R19 prep_mt fusion REGRESSED (latency-bound Mt). R20 XCD
// swizzle scores/PV WIN 217->204. R21 scores2wz(2-wave 64x64)+mt64 WIN
// 201.9. R22 TV-swizzle REGRESSED (212.5; TV reads L3-absorbed, writes
// inflate). R23 tv2-unswizzled 203.3. R25 per-stripe 2-wave PV REGRESSED
// (+18; 16:1 imbalance, full-grid residency = no refill). R26 paired 2-wave
// PV REGRESSED (+5; 4 waves/CU TLP floor). PV stays on stripe-paired 4-wave
// gemm_bt<3>; scores on 2-wave scores2wz; TV on gemm_tv8 as-compiled here.

// ---------------- baseline 2-barrier GEMM (mode 3 = PV) ----------------
// C = A[M][K] * B[N][K]^T, bf16 in, fp32 accum. 128x64 tile, 4 waves.
// MODE 3: PV, stripe pairs p: seg0 = stripe 15-p (K=128*(16-p)), seg1 =
//         stripe p (K=128*(p+1)); out = C / rsum[row];
//         XCD swizzle over flat = x + 16*y + 128*z (512 blocks)
template<int MODE>
__global__ __launch_bounds__(256, 4)
void gemm_bt(const unsigned short* __restrict__ A,
             const unsigned short* __restrict__ Bm,
             float* __restrict__ Cf,
             float* __restrict__ Cf2,
             unsigned short* __restrict__ Cb,
             int K, long aBatch, long bBatch, long cBatch, float scale)
{
  constexpr int NI    = 2;
  constexpr int BROWS = 16;
  constexpr int BG    = 2;

  int z, bm0 = 0, bn, p = 0;
  if (MODE == 3) {
    int flat = blockIdx.x + 16 * blockIdx.y + 128 * blockIdx.z;  // 512 total
    int rm   = (flat & 7) * 64 + (flat >> 3);      // bijective
    z  = rm >> 7;
    p  = (rm >> 4) & 7;
    bn = (rm & 15) * 64;
  } else {
    z   = blockIdx.z;
    bm0 = blockIdx.y * 128;
    bn  = blockIdx.x * 64;
  }

  A  += (long)z * aBatch;
  Bm += (long)z * bBatch;
  if (MODE == 3) { Cf += (long)z * cBatch; Cf2 += (long)z * 2048; }

  __shared__ __align__(16) unsigned short As[128 * BK];
  __shared__ __align__(16) unsigned short Bs[64 * BK];

  int tid  = threadIdx.x;
  int wave = tid >> 6, lane = tid & 63;
  int wm = wave * 32;
  int quad = lane >> 4, l16 = lane & 15;

  // staging lane coords: 8-row groups, chunk XOR-swizzled (row%8-invariant)
  int r8 = lane >> 3;
  int c  = (lane & 7) ^ r8;
  const unsigned short* Bg = Bm + (long)(bn + wave * BROWS + r8) * K + c * 8;
  unsigned short* Al = &As[(wave * 32) * BK];
  unsigned short* Bl = &Bs[(wave * BROWS) * BK];

  const int nseg = (MODE == 3) ? 2 : 1;
  for (int seg = 0; seg < nseg; seg++) {
    int bm   = (MODE == 3) ? ((seg == 0) ? (15 - p) * 128 : p * 128) : bm0;
    int Keff = (MODE == 3) ? ((seg == 0) ? 128 * (16 - p) : 128 * (p + 1)) : K;
    const unsigned short* Ag = A + (long)(bm + wave * 32 + r8) * K + c * 8;

    f32x4 acc[NI][4] = {};

    for (int k0 = 0; k0 < Keff; k0 += BK) {
#pragma unroll
      for (int g = 0; g < 4; g++)
        gload16(Ag + k0 + (long)g * 8 * K, Al + g * 8 * BK);
#pragma unroll
      for (int g = 0; g < BG; g++)
        gload16(Bg + k0 + (long)g * 8 * K, Bl + g * 8 * BK);
      __syncthreads();

#pragma unroll
      for (int h = 0; h < 2; h++) {
        bf16x8 af[NI], bfr[4];
#pragma unroll
        for (int i = 0; i < NI; i++)
          af[i]  = *(const bf16x8*)&As[(wm + i * 16 + l16) * BK + (((quad + 4 * h) ^ (l16 & 7)) * 8)];
#pragma unroll
        for (int j = 0; j < 4; j++)
          bfr[j] = *(const bf16x8*)&Bs[(j * 16 + l16) * BK + (((quad + 4 * h) ^ (l16 & 7)) * 8)];
#pragma unroll
        for (int i = 0; i < NI; i++)
#pragma unroll
          for (int j = 0; j < 4; j++)
            acc[i][j] = __builtin_amdgcn_mfma_f32_16x16x32_bf16(af[i], bfr[j], acc[i][j], 0, 0, 0);
      }
      __syncthreads();
    }

    // Epilogue. C/D layout: col = lane&15, row = quad*4 + reg  [m89/m91]
#pragma unroll
    for (int i = 0; i < NI; i++) {
      int grow0 = bm + wm + i * 16 + quad * 4;
      if (MODE == 3) {
        float rinv[4];
#pragma unroll
        for (int r = 0; r < 4; r++) rinv[r] = 1.0f / Cf2[grow0 + r];
#pragma unroll
        for (int j = 0; j < 4; j++) {
          int gcol = bn + j * 16 + l16;
#pragma unroll
          for (int r = 0; r < 4; r++)
            Cf[(long)(grow0 + r) * 1024 + gcol] = acc[i][j][r] * rinv[r];
        }
      } else {
#pragma unroll
        for (int j = 0; j < 4; j++) {
          int gcol = bn + j * 16 + l16;
#pragma unroll
          for (int r = 0; r < 4; r++)
            Cb[(long)(grow0 + r) * 1024 + gcol] = f2bf(acc[i][j][r]);
        }
      }
    }
  }
}

// ---------------- R21: Mt on 64x64 tiles, full-GPU grid ----------------
// Mt[j][i] = sum_o Wkb[j][o] Wqb[i][o]. 256 blocks (16x16), 256 thr, 4 waves
// each owning 16m x 64n. LDS 16KB. Same XOR-chunk swizzle as gemm_bt.
__global__ __launch_bounds__(256, 4)
void mt64(const unsigned short* __restrict__ Wkb,
          const unsigned short* __restrict__ Wqb,
          unsigned short* __restrict__ Mt)
{
  int bm = blockIdx.y * 64, bn = blockIdx.x * 64;
  __shared__ __align__(16) unsigned short As[64 * 64];
  __shared__ __align__(16) unsigned short Bs[64 * 64];

  int tid  = threadIdx.x;
  int wave = tid >> 6, lane = tid & 63;
  int quad = lane >> 4, l16 = lane & 15;
  int r8 = lane >> 3;
  int c  = (lane & 7) ^ r8;
  const unsigned short* Ag = Wkb + (long)(bm + wave * 16 + r8) * 1024 + c * 8;
  const unsigned short* Bg = Wqb + (long)(bn + wave * 16 + r8) * 1024 + c * 8;
  unsigned short* Al = &As[(wave * 16) * 64];
  unsigned short* Bl = &Bs[(wave * 16) * 64];

  f32x4 acc[4] = {};

  for (int k0 = 0; k0 < 1024; k0 += 64) {
#pragma unroll
    for (int g = 0; g < 2; g++)
      gload16(Ag + k0 + (long)g * 8 * 1024, Al + g * 8 * 64);
#pragma unroll
    for (int g = 0; g < 2; g++)
      gload16(Bg + k0 + (long)g * 8 * 1024, Bl + g * 8 * 64);
    __syncthreads();

#pragma unroll
    for (int h = 0; h < 2; h++) {
      bf16x8 af, bfr[4];
      af = *(const bf16x8*)&As[(wave * 16 + l16) * 64 + (((quad + 4 * h) ^ (l16 & 7)) * 8)];
#pragma unroll
      for (int j = 0; j < 4; j++)
        bfr[j] = *(const bf16x8*)&Bs[(j * 16 + l16) * 64 + (((quad + 4 * h) ^ (l16 & 7)) * 8)];
#pragma unroll
      for (int j = 0; j < 4; j++)
        acc[j] = __builtin_amdgcn_mfma_f32_16x16x32_bf16(af, bfr[j], acc[j], 0, 0, 0);
    }
    __syncthreads();
  }

  int grow0 = bm + wave * 16 + quad * 4;
#pragma unroll
  for (int j = 0; j < 4; j++) {
    int gcol = bn + j * 16 + l16;
#pragma unroll
    for (int r = 0; r < 4; r++)
      Mt[(long)(grow0 + r) * 1024 + gcol] = f2bf(acc[j][r]);
  }
}

// ---------------- R21: scores, 2-wave blocks + XCD swizzle ----------------
// Per-wave 64x64 output (TV's MFMA-bound geometry: 32 MFMA vs 12 ds_read per
// K-step), block tile 128x64, 1088-block tri grid, LDS 24KB. R16 proved
// correctness; R21 adds the tri-flat XCD swizzle (post-swizzle loads are
// L2-hits -> the TLP-loss that nulled R16 is gone).
__global__ __launch_bounds__(128, 3)
void scores2wz(const unsigned short* __restrict__ T,   // [b][2048][1024]
               const unsigned short* __restrict__ Xb,  // [b][2048][1024]
               float* __restrict__ rsum,               // [b][2048]
               unsigned short* __restrict__ E,         // [b][2048][2048]
               float scale)
{
  // XCD swizzle then triangular decode over 128x64 tiles (272/batch)
  int flat = blockIdx.x + 272 * blockIdx.z;        // 1088 total
  int rm   = (flat & 7) * 136 + (flat >> 3);       // bijective
  int z = rm / 272;
  int f = rm % 272;
  int r = (int)((sqrtf((float)(4 * f + 1)) - 1.0f) * 0.5f);
  while ((r + 1) * (r + 2) <= f) r++;
  while (r * (r + 1) > f) r--;
  int bm0 = r * 128;
  int bn  = (f - r * (r + 1)) * 64;

  const unsigned short* A = T  + (long)z * 2048 * 1024;
  const unsigned short* B = Xb + (long)z * 2048 * 1024;
  unsigned short* Cb = E + (long)z * 2048 * 2048;
  float* Cf = rsum + (long)z * 2048;

  __shared__ __align__(16) unsigned short As[128 * BK];  // 16 KB
  __shared__ __align__(16) unsigned short Bs[64 * BK];   //  8 KB

  int tid  = threadIdx.x;
  int wave = tid >> 6, lane = tid & 63;
  int quad = lane >> 4, l16 = lane & 15;
  int wm   = wave * 64;                 // wave owns 64 rows x all 64 cols

  // staging lane coords: 8-row groups, chunk XOR-swizzled (row%8-invariant)
  int r8 = lane >> 3;
  int c  = (lane & 7) ^ r8;
  const unsigned short* Ag = A + (long)(bm0 + wave * 64 + r8) * 1024 + c * 8;
  const unsigned short* Bg = B + (long)(bn  + wave * 32 + r8) * 1024 + c * 8;
  unsigned short* Al = &As[(wave * 64) * BK];
  unsigned short* Bl = &Bs[(wave * 32) * BK];

  f32x4 acc[4][4] = {};

  for (int k0 = 0; k0 < 1024; k0 += BK) {
#pragma unroll
    for (int g = 0; g < 8; g++)        // A: 64 rows per wave
      gload16(Ag + k0 + (long)g * 8 * 1024, Al + g * 8 * BK);
#pragma unroll
    for (int g = 0; g < 4; g++)        // B: 32 rows per wave
      gload16(Bg + k0 + (long)g * 8 * 1024, Bl + g * 8 * BK);
    __syncthreads();

#pragma unroll
    for (int h = 0; h < 2; h++) {
      bf16x8 af[4], bfr[4];
#pragma unroll
      for (int i = 0; i < 4; i++)
        af[i]  = *(const bf16x8*)&As[(wm + i * 16 + l16) * BK + (((quad + 4 * h) ^ (l16 & 7)) * 8)];
#pragma unroll
      for (int j = 0; j < 4; j++)
        bfr[j] = *(const bf16x8*)&Bs[(j * 16 + l16) * BK + (((quad + 4 * h) ^ (l16 & 7)) * 8)];
#pragma unroll
      for (int i = 0; i < 4; i++)
#pragma unroll
        for (int j = 0; j < 4; j++)
          acc[i][j] = __builtin_amdgcn_mfma_f32_16x16x32_bf16(af[i], bfr[j], acc[i][j], 0, 0, 0);
    }
    __syncthreads();
  }

  // Epilogue: E = exp(C*scale) masked col<=row + row-sum atomics
#pragma unroll
  for (int i = 0; i < 4; i++) {
    int grow0 = bm0 + wm + i * 16 + quad * 4;
#pragma unroll
    for (int rr = 0; rr < 4; rr++) {
      int grow = grow0 + rr;
      float rowpart = 0.f;
#pragma unroll
      for (int j = 0; j < 4; j++) {
        int gcol = bn + j * 16 + l16;
        float e = (gcol <= grow) ? __expf(acc[i][j][rr] * scale) : 0.f;
        rowpart += e;
        Cb[(long)grow * 2048 + gcol] = f2bf(e);
      }
      rowpart += __shfl_xor(rowpart, 1);
      rowpart += __shfl_xor(rowpart, 2);
      rowpart += __shfl_xor(rowpart, 4);
      rowpart += __shfl_xor(rowpart, 8);
      if (l16 == 0) atomicAdd(&Cf[grow], rowpart);
    }
  }
}

// ---------------- 8-phase 256x256 fused TV (R18 + R20 swizzle) ----------
__global__ __launch_bounds__(512, 2)
void gemm_tv8(const unsigned short* __restrict__ A,   // Xb [8192][1024]
              const unsigned short* __restrict__ Bm,  // TVB [2048][1024]
              unsigned short* __restrict__ Cb)        // T ; Vt
{
  constexpr int NT = 16;                 // K tiles (1024 / 64)
  constexpr int SLOT = 256 * 64;         // shorts per operand buffer
  __shared__ __align__(16) unsigned short AsL[2 * SLOT];
  __shared__ __align__(16) unsigned short BsL[2 * SLOT];

  const int tid  = threadIdx.x;
  const int wave = tid >> 6, lane = tid & 63;
  const int quad = lane >> 4, l16 = lane & 15;
  const int wr = wave >> 2, wc = wave & 3;
  // XCD swizzle: flat = x + 8*y (256 blocks); XCD k gets 4 consecutive
  // m-panels x all 8 n-blocks -> A-panel L2-resident per XCD.
  const int flat = blockIdx.x + 8 * blockIdx.y;
  const int rm   = (flat & 7) * 32 + (flat >> 3);
  const int bm = (rm >> 3) * 256;
  const int bn = (rm & 7) * 256;

  // staging coords: lane -> (row l8, source chunk sc), XOR chunk swizzle so
  // LDS[row][p] = global[row][p ^ (row&7)] with linear gload dest.
  const int l8 = lane >> 3;
  const int sc = ((lane & 7) ^ l8) * 8;
  const unsigned short* Ag = A  + (long)(bm + wave * 8 + l8) * 1024 + sc;
  const unsigned short* Bg = Bm + (long)(bn + (wave >> 2) * 64 + (wave & 3) * 8 + l8) * 1024 + sc;

#define STGA(base, h, t) {                                                      \
    gload16(Ag + (long)((h) * 64) * 1024 + (t) * 64,        (base) + ((h) * 128 + wave * 8) * 64);      \
    gload16(Ag + (long)(128 + (h) * 64) * 1024 + (t) * 64,  (base) + ((h) * 128 + 64 + wave * 8) * 64); }
#define STGB(base, h, t) {                                                      \
    gload16(Bg + (long)((h) * 32) * 1024 + (t) * 64,        (base) + ((h) * 128 + wave * 8) * 64);      \
    gload16(Bg + (long)(128 + (h) * 32) * 1024 + (t) * 64,  (base) + ((h) * 128 + 64 + wave * 8) * 64); }

#define RD_A(afX, src, qm) _Pragma("unroll") for (int i = 0; i < 4; ++i)        \
    _Pragma("unroll") for (int h2 = 0; h2 < 2; ++h2)                            \
      afX[i][h2] = *(const bf16x8*)&(src)[((qm) * 128 + wr * 64 + i * 16 + l16) * 64 + (((quad + 4 * h2) ^ (l16 & 7)) * 8)];
#define RD_B(bfX, src, qn) _Pragma("unroll") for (int j = 0; j < 2; ++j)        \
    _Pragma("unroll") for (int h2 = 0; h2 < 2; ++h2)                            \
      bfX[j][h2] = *(const bf16x8*)&(src)[((qn) * 128 + wc * 32 + j * 16 + l16) * 64 + (((quad + 4 * h2) ^ (l16 & 7)) * 8)];
#define MFMA16(afX, bfX, MI0, NJ0) {                                            \
    __builtin_amdgcn_s_setprio(1);                                              \
    _Pragma("unroll") for (int i = 0; i < 4; ++i)                               \
      _Pragma("unroll") for (int j = 0; j < 2; ++j)                             \
        _Pragma("unroll") for (int h2 = 0; h2 < 2; ++h2)                        \
          acc[(MI0) + i][(NJ0) + j] =                                           \
            __builtin_amdgcn_mfma_f32_16x16x32_bf16(afX[i][h2], bfX[j][h2], acc[(MI0) + i][(NJ0) + j], 0, 0, 0); \
    __builtin_amdgcn_s_setprio(0); }

  f32x4 acc[8][4] = {};

  // prologue: tile0 all 4 halves + tile1's Bh0,Ah1
  STGA(AsL, 0, 0) STGB(BsL, 0, 0)
  STGA(AsL, 1, 0) STGB(BsL, 1, 0)
  STGB(BsL + SLOT, 0, 1) STGA(AsL + SLOT, 1, 1)
  asm volatile("s_waitcnt vmcnt(4)" ::: "memory");   // tile0 landed
  __builtin_amdgcn_sched_barrier(0);
  __builtin_amdgcn_s_barrier();

#pragma unroll 1
  for (int u = 0; u < NT; ++u) {
    const int b = u & 1;
    const unsigned short* Asb = AsL + b * SLOT;
    const unsigned short* Bsb = BsL + b * SLOT;
    unsigned short* Asn = AsL + (b ^ 1) * SLOT;
    unsigned short* Bsn = BsL + (b ^ 1) * SLOT;
    unsigned short* Asc = AsL + b * SLOT;
    unsigned short* Bsc = BsL + b * SLOT;

    bf16x8 af0[4][2], af1[4][2], bf0[2][2], bf1[2][2];

    // ---- phase 0: (qm=0,qn=0) ----
    RD_A(af0, Asb, 0)
    RD_B(bf0, Bsb, 0)
    if (u + 1 < NT) { STGA(Asn, 0, u + 1) STGB(Bsn, 1, u + 1) }
    __builtin_amdgcn_s_barrier();
    MFMA16(af0, bf0, 0, 0)
    __builtin_amdgcn_s_barrier();

    // ---- phase 1: (1,0) reuse bf0 ----
    RD_A(af1, Asb, 1)
    if (u + 2 < NT) STGB(Bsc, 0, u + 2)
    __builtin_amdgcn_s_barrier();
    MFMA16(af1, bf0, 4, 0)
    __builtin_amdgcn_s_barrier();

    // ---- phase 2: (1,1) reuse af1 ----
    RD_B(bf1, Bsb, 1)
    if (u + 2 < NT) STGA(Asc, 1, u + 2)
    __builtin_amdgcn_s_barrier();
    MFMA16(af1, bf1, 4, 2)
    __builtin_amdgcn_s_barrier();

    // ---- phase 3: (0,1) reuse af0,bf1; counted wait for next tile ----
    if (u < NT - 2)       { asm volatile("s_waitcnt vmcnt(4)" ::: "memory"); }
    else if (u == NT - 2) { asm volatile("s_waitcnt vmcnt(0)" ::: "memory"); }
    __builtin_amdgcn_sched_barrier(0);
    __builtin_amdgcn_s_barrier();
    MFMA16(af0, bf1, 0, 2)
    __builtin_amdgcn_s_barrier();
  }
#undef STGA
#undef STGB
#undef RD_A
#undef RD_B
#undef MFMA16

  // TV split epilogue
#pragma unroll
  for (int mi = 0; mi < 8; ++mi) {
    int grow0 = bm + wr * 128 + mi * 16 + quad * 4;
#pragma unroll
    for (int nj = 0; nj < 4; ++nj) {
      int gcol = bn + wc * 64 + nj * 16 + l16;
      int which = gcol >> 10;           // wave-uniform
      int col = gcol & 1023;
      if (which == 0) {                 // T bf16 row-major [8192][1024]
#pragma unroll
        for (int r = 0; r < 4; r++)
          Cb[(long)(grow0 + r) * 1024 + col] = f2bf(acc[mi][nj][r]);
      } else {                          // Vt[b][col][s], 4-row pack along s
        unsigned short* Vt = Cb + (long)8192 * 1024;
        int bb = grow0 >> 11, s = grow0 & 2047;
        ushort4 pk;
        pk.x = f2bf(acc[mi][nj][0]); pk.y = f2bf(acc[mi][nj][1]);
        pk.z = f2bf(acc[mi][nj][2]); pk.w = f2bf(acc[mi][nj][3]);
        *(ushort4*)(Vt + ((long)bb * 1024 + col) * 2048 + s) = pk;
      }
    }
  }
}

// fused prep: [0,8192) x->bf16; [8192,9216) Wq->bf16 (NO transpose);
// [9216,10240) Wk->bf16 (NO transpose); [10240,11264) Wv transpose-convert;
// [11264,11272) zero rsum
__global__ __launch_bounds__(256)
void prep(const float* __restrict__ x,
          const float* __restrict__ W0, const float* __restrict__ W1,
          const float* __restrict__ W2,
          unsigned short* __restrict__ Xb,
          unsigned short* __restrict__ Wqb, unsigned short* __restrict__ Wkb,
          unsigned short* __restrict__ WvT,
          float* __restrict__ rsum)
{
  __shared__ float tile[32][33];
  int b = blockIdx.x;
  if (b < 8192) {
    long i = ((long)b * 256 + threadIdx.x) * 4;
    float4 v = *(const float4*)(x + i);
    ushort4 o;
    o.x = f2bf(v.x); o.y = f2bf(v.y); o.z = f2bf(v.z); o.w = f2bf(v.w);
    *(ushort4*)(Xb + i) = o;
  } else if (b < 10240) {
    int t = b - 8192;
    const float* W    = (t < 1024) ? W0 : W1;
    unsigned short* D = (t < 1024) ? Wqb : Wkb;
    long i = ((long)(t & 1023) * 256 + threadIdx.x) * 4;
    float4 v = *(const float4*)(W + i);
    ushort4 o;
    o.x = f2bf(v.x); o.y = f2bf(v.y); o.z = f2bf(v.z); o.w = f2bf(v.w);
    *(ushort4*)(D + i) = o;
  } else if (b < 11264) {
    int q = b - 10240;
    int kb = (q >> 5) * 32, nb = (q & 31) * 32;
    int tx = threadIdx.x & 31, ty = threadIdx.x >> 5;
    for (int r = ty; r < 32; r += 8)
      tile[r][tx] = W2[(long)(kb + r) * 1024 + nb + tx];
    __syncthreads();
    for (int r = ty; r < 32; r += 8)
      WvT[(long)(nb + r) * 1024 + kb + tx] = f2bf(tile[tx][r]);
  } else {
    long i = ((long)(b - 11264) * 256 + threadIdx.x) * 4;
    float4 zz = {0.f, 0.f, 0.f, 0.f};
    *(float4*)(rsum + i) = zz;
  }
}

extern "C" void kernel_launch(void* const* d_in, const int* in_sizes, int n_in,
                              void* d_out, int out_size, void* d_ws, size_t ws_size,
                              hipStream_t stream) {
  const float* x  = (const float*)d_in[0];
  const float* Wq = (const float*)d_in[1];
  const float* Wk = (const float*)d_in[2];
  const float* Wv = (const float*)d_in[3];
  float* out = (float*)d_out;

  // workspace layout (bf16 = unsigned short), ~120 MB
  unsigned short* Xb  = (unsigned short*)d_ws;            // [8192][1024]
  unsigned short* Wqb = Xb  + (long)8192 * 1024;          // [1024][1024] bf16 [in][out]
  unsigned short* Wkb = Wqb + (long)1024 * 1024;          // [1024][1024] bf16 [in][out]
  unsigned short* TVB = Wkb + (long)1024 * 1024;          // [2048][1024]: Mt ; WvT
  unsigned short* T   = TVB + (long)2048 * 1024;          // [8192][1024]
  unsigned short* Vt  = T   + (long)8192 * 1024;          // [4][1024][2048] (follows T!)
  unsigned short* E   = Vt  + (long)8192 * 1024;          // [4][2048][2048] bf16 exp(s)
  float* rsum         = (float*)(E + (long)4 * 2048 * 2048); // [4][2048] fp32

  prep<<<11272, 256, 0, stream>>>(x, Wq, Wk, Wv, Xb, Wqb, Wkb,
                                  TVB + (long)1024 * 1024, rsum);

  // Mt[j][i] = sum_o Wk[j][o] Wq[i][o] = M[i][j], M = Wq Wk^T (full-GPU grid)
  mt64<<<dim3(16, 16, 1), 256, 0, stream>>>(Wkb, Wqb, TVB);

  // fused TV: [8192x2048] = Xb * [Mt;WvT]^T on the 8-phase 256^2 schedule
  gemm_tv8<<<dim3(8, 32, 1), 512, 0, stream>>>(Xb, TVB, T);

  // E = exp(T * Xb^T / 32) masked lower-tri + row sums; 2-wave + XCD swizzle
  scores2wz<<<dim3(272, 1, 4), 128, 0, stream>>>(T, Xb, rsum, E, 0.03125f);

  // out = (E * Vt^T)/rsum; stripe pairs (15-p, p) + XCD swizzle
  gemm_bt<3><<<dim3(16, 8, 4), 256, 0, stream>>>(E, Vt, out, rsum, nullptr, 2048,
      (long)2048 * 2048, (long)1024 * 2048, (long)2048 * 1024, 1.f);
}